// Round 5
// baseline (341.523 us; speedup 1.0000x reference)
//
#include <hip/hip_runtime.h>
#include <hip/hip_bf16.h>

#define N_NODES 100000
#define N_EDGES 1600000
#define IN_FEA 128
#define HIDDEN 128
#define RANK 64

#define NBUCK 391          // ceil(N_NODES/256): bucket b = nodes [b*256, b*256+256)
#define C_BLOCKS 1024
#define EPB 1563           // ceil(N_EDGES / C_BLOCKS)

// ---------------- CSR build: binned counting sort ----------------

__global__ __launch_bounds__(256) void bucket_hist_kernel(const int* __restrict__ dst,
                                                          int* __restrict__ bhist,
                                                          int* __restrict__ blockhist) {
    __shared__ int hist[NBUCK];
    int t = threadIdx.x;
    for (int i = t; i < NBUCK; i += 256) hist[i] = 0;
    __syncthreads();
    int b0 = blockIdx.x * EPB;
    int b1 = min(b0 + EPB, N_EDGES);
    for (int e = b0 + t; e < b1; e += 256)
        atomicAdd(&hist[dst[e] >> 8], 1);
    __syncthreads();
    for (int i = t; i < NBUCK; i += 256) {
        int c = hist[i];
        blockhist[blockIdx.x * NBUCK + i] = c;
        if (c) atomicAdd(&bhist[i], c);
    }
}

__global__ void bucket_scan_kernel(const int* __restrict__ bhist,
                                   int* __restrict__ bucket_offs,
                                   int* __restrict__ bucket_cursor,
                                   int* __restrict__ offs) {
    __shared__ int sd[512];
    int t = threadIdx.x;
    int v = (t < NBUCK) ? bhist[t] : 0;
    sd[t] = v;
    __syncthreads();
    for (int off = 1; off < 512; off <<= 1) {
        int a = 0;
        if (t >= off) a = sd[t - off];
        __syncthreads();
        sd[t] += a;
        __syncthreads();
    }
    if (t < NBUCK) {
        int excl = sd[t] - v;
        bucket_offs[t] = excl;
        bucket_cursor[t] = excl;
    }
    if (t == 0) {
        bucket_offs[NBUCK] = N_EDGES;
        offs[N_NODES] = N_EDGES;
    }
}

__global__ __launch_bounds__(256) void binscatter_kernel(const int* __restrict__ src,
                                                         const int* __restrict__ dst,
                                                         const int* __restrict__ blockhist,
                                                         int* __restrict__ bucket_cursor,
                                                         unsigned* __restrict__ pairs) {
    __shared__ int wbase[NBUCK];
    __shared__ int cur[NBUCK];
    int t = threadIdx.x;
    for (int i = t; i < NBUCK; i += 256) {
        int c = blockhist[blockIdx.x * NBUCK + i];
        wbase[i] = c ? atomicAdd(&bucket_cursor[i], c) : 0;
        cur[i] = 0;
    }
    __syncthreads();
    int b0 = blockIdx.x * EPB;
    int b1 = min(b0 + EPB, N_EDGES);
    for (int e = b0 + t; e < b1; e += 256) {
        int d = dst[e];
        int s = src[e];
        int bk = d >> 8;
        int lp = atomicAdd(&cur[bk], 1);
        pairs[wbase[bk] + lp] = ((unsigned)s << 8) | (unsigned)(d & 255);
    }
}

__global__ __launch_bounds__(256) void bucket_build_kernel(const unsigned* __restrict__ pairs,
                                                           const int* __restrict__ bucket_offs,
                                                           int* __restrict__ offs,
                                                           int* __restrict__ eidx) {
    __shared__ int dcnt[256];
    __shared__ int sd[256];
    __shared__ int cur[256];
    int b = blockIdx.x, t = threadIdx.x;
    int base = bucket_offs[b], end = bucket_offs[b + 1];
    dcnt[t] = 0;
    __syncthreads();
    for (int i = base + t; i < end; i += 256)
        atomicAdd(&dcnt[pairs[i] & 255u], 1);
    __syncthreads();
    int v = dcnt[t];
    sd[t] = v;
    __syncthreads();
    for (int off = 1; off < 256; off <<= 1) {
        int a = 0;
        if (t >= off) a = sd[t - off];
        __syncthreads();
        sd[t] += a;
        __syncthreads();
    }
    int excl = sd[t] - v;
    int node = b * 256 + t;
    if (node < N_NODES) offs[node] = base + excl;
    cur[t] = excl;
    __syncthreads();
    for (int i = base + t; i < end; i += 256) {
        unsigned r = pairs[i];
        int lp = atomicAdd(&cur[r & 255u], 1);
        eidx[base + lp] = (int)(r >> 8);
    }
}

// ---------------- helpers ----------------

__device__ __forceinline__ void fma4(float4& a, float s, const float4& b) {
    a.x = fmaf(s, b.x, a.x);
    a.y = fmaf(s, b.y, a.y);
    a.z = fmaf(s, b.z, a.z);
    a.w = fmaf(s, b.w, a.w);
}

__device__ __forceinline__ unsigned short f2bf_rne(float f) {
    unsigned u = __float_as_uint(f);
    u += 0x7fffu + ((u >> 16) & 1u);
    return (unsigned short)(u >> 16);
}

__device__ __forceinline__ float bf2f(unsigned short s) {
    return __uint_as_float(((unsigned)s) << 16);
}

// ---------------- GEMM1: h_bf = bf16(x @ W)  [N,128]x[128,64] ----------------
// 32 nodes/block; 2 nodes x 4 ranks per thread; W in LDS.

__global__ __launch_bounds__(256) void gemm1_kernel(const float* __restrict__ x,
                                                    const float* __restrict__ W,
                                                    unsigned short* __restrict__ hb) {
    __shared__ float Wl[IN_FEA * RANK];  // 32 KB
    int t = threadIdx.x;
    for (int i = t; i < IN_FEA * RANK; i += 256) Wl[i] = W[i];
    __syncthreads();

    int wave = t >> 6, lane = t & 63;
    int node0 = blockIdx.x * 32 + wave * 8 + (lane >> 4) * 2;
    int r0 = (lane & 15) * 4;

    const float4* xa = (const float4*)(x + (long)node0 * IN_FEA);
    const float4* xb = (const float4*)(x + (long)(node0 + 1) * IN_FEA);
    float4 acca = {0.f, 0.f, 0.f, 0.f};
    float4 accb = {0.f, 0.f, 0.f, 0.f};
    for (int k4 = 0; k4 < IN_FEA / 4; ++k4) {
        float4 va = xa[k4];
        float4 vb = xb[k4];
        int kb = k4 * 4;
        float4 w0 = *(const float4*)&Wl[(kb + 0) * RANK + r0];
        float4 w1 = *(const float4*)&Wl[(kb + 1) * RANK + r0];
        float4 w2 = *(const float4*)&Wl[(kb + 2) * RANK + r0];
        float4 w3 = *(const float4*)&Wl[(kb + 3) * RANK + r0];
        fma4(acca, va.x, w0); fma4(accb, vb.x, w0);
        fma4(acca, va.y, w1); fma4(accb, vb.y, w1);
        fma4(acca, va.z, w2); fma4(accb, vb.z, w2);
        fma4(acca, va.w, w3); fma4(accb, vb.w, w3);
    }
    ushort4 oa, ob;
    oa.x = f2bf_rne(acca.x); oa.y = f2bf_rne(acca.y);
    oa.z = f2bf_rne(acca.z); oa.w = f2bf_rne(acca.w);
    ob.x = f2bf_rne(accb.x); ob.y = f2bf_rne(accb.y);
    ob.z = f2bf_rne(accb.z); ob.w = f2bf_rne(accb.w);
    *(ushort4*)(hb + node0 * RANK + r0) = oa;
    *(ushort4*)(hb + (node0 + 1) * RANK + r0) = ob;
}

// ---------------- fused aggregation + GEMM2 ----------------
// 256 threads = 4 waves; 4 nodes per wave (16 nodes/block). Grid = 6250.
// Phase 1 (per wave): products for 4 nodes, lane = rank (bf16 h gather, 128 B/row).
// Phase 2: wave-private trans rows -> LDS, mini-GEMM vs V (LDS, padded stride 66).

__global__ __launch_bounds__(256) void agg_gemm_kernel(const unsigned short* __restrict__ hb,
                                                       const float* __restrict__ norm,
                                                       const float* __restrict__ V,
                                                       const int* __restrict__ offs,
                                                       const int* __restrict__ eidx,
                                                       float* __restrict__ out) {
    __shared__ float VL[128 * 66];      // 33,792 B: VL[j*66 + r] = V[j][r], 2-way banks = free
    __shared__ float4 pls[256];         // 4 KB: per-wave 64-slot trans staging
    int t = threadIdx.x;
#pragma unroll
    for (int k = 0; k < 32; ++k) {
        int idx = t + 256 * k;          // coalesced read, stride-1 LDS write
        VL[(idx >> 6) * 66 + (idx & 63)] = V[idx];
    }

    int wave = t >> 6, lane = t & 63;
    int base = blockIdx.x * 16 + wave * 4;

    float p[4];
#pragma unroll
    for (int i = 0; i < 4; ++i) {
        int node = base + i;
        int beg = offs[node], end = offs[node + 1];
        float pp = 1.0f;
        for (int c = beg; c < end; c += 64) {
            int n = min(64, end - c);
            int sidx = (c + lane < end) ? eidx[c + lane] : 0;
            int j = 0;
            for (; j + 8 <= n; j += 8) {
                int s0 = __shfl(sidx, j + 0);
                int s1 = __shfl(sidx, j + 1);
                int s2 = __shfl(sidx, j + 2);
                int s3 = __shfl(sidx, j + 3);
                int s4 = __shfl(sidx, j + 4);
                int s5 = __shfl(sidx, j + 5);
                int s6 = __shfl(sidx, j + 6);
                int s7 = __shfl(sidx, j + 7);
                float a0 = bf2f(hb[s0 * RANK + lane]);
                float a1 = bf2f(hb[s1 * RANK + lane]);
                float a2 = bf2f(hb[s2 * RANK + lane]);
                float a3 = bf2f(hb[s3 * RANK + lane]);
                float a4 = bf2f(hb[s4 * RANK + lane]);
                float a5 = bf2f(hb[s5 * RANK + lane]);
                float a6 = bf2f(hb[s6 * RANK + lane]);
                float a7 = bf2f(hb[s7 * RANK + lane]);
                pp *= ((a0 * a1) * (a2 * a3)) * ((a4 * a5) * (a6 * a7));
            }
            for (; j < n; ++j) {
                int s = __shfl(sidx, j);
                pp *= bf2f(hb[s * RANK + lane]);
            }
        }
        p[i] = pp * norm[node];
    }

    float4 pv;
    pv.x = p[0]; pv.y = p[1]; pv.z = p[2]; pv.w = p[3];
    pls[wave * 64 + lane] = pv;
    __syncthreads();   // covers V staging + pls visibility

    float2 acc0 = {0.f, 0.f}, acc1 = {0.f, 0.f}, acc2 = {0.f, 0.f}, acc3 = {0.f, 0.f};
    const float4* pw = &pls[wave * 64];
    const float* va_row = &VL[lane * 66];
    const float* vb_row = &VL[(lane + 64) * 66];
#pragma unroll 8
    for (int r = 0; r < RANK; ++r) {
        float4 pp = pw[r];              // broadcast read
        float va = va_row[r];
        float vb = vb_row[r];
        acc0.x = fmaf(pp.x, va, acc0.x); acc0.y = fmaf(pp.x, vb, acc0.y);
        acc1.x = fmaf(pp.y, va, acc1.x); acc1.y = fmaf(pp.y, vb, acc1.y);
        acc2.x = fmaf(pp.z, va, acc2.x); acc2.y = fmaf(pp.z, vb, acc2.y);
        acc3.x = fmaf(pp.w, va, acc3.x); acc3.y = fmaf(pp.w, vb, acc3.y);
    }
    out[(base + 0) * HIDDEN + lane] = acc0.x;
    out[(base + 0) * HIDDEN + 64 + lane] = acc0.y;
    out[(base + 1) * HIDDEN + lane] = acc1.x;
    out[(base + 1) * HIDDEN + 64 + lane] = acc1.y;
    out[(base + 2) * HIDDEN + lane] = acc2.x;
    out[(base + 2) * HIDDEN + 64 + lane] = acc2.y;
    out[(base + 3) * HIDDEN + lane] = acc3.x;
    out[(base + 3) * HIDDEN + 64 + lane] = acc3.y;
}

// ---------------- launch ----------------

extern "C" void kernel_launch(void* const* d_in, const int* in_sizes, int n_in,
                              void* d_out, int out_size, void* d_ws, size_t ws_size,
                              hipStream_t stream) {
    const float* x    = (const float*)d_in[0];
    const float* norm = (const float*)d_in[1];
    const float* W    = (const float*)d_in[2];
    const float* V    = (const float*)d_in[3];
    const int*   src  = (const int*)d_in[4];
    const int*   dst  = (const int*)d_in[5];
    float* out = (float*)d_out;

    // workspace layout (ws): hb (bf16), offs, eidx, small bucket arrays
    unsigned short* hb = (unsigned short*)d_ws;              // N*RANK bf16 (12.8 MB)
    int*   offs        = (int*)(hb + (long)N_NODES * RANK);  // N+1
    int*   eidx        = offs + N_NODES + 1;                 // E
    int*   bhist       = eidx + N_EDGES;                     // NBUCK
    int*   bucket_offs = bhist + NBUCK;                      // NBUCK+1
    int*   bucket_cur  = bucket_offs + NBUCK + 1;            // NBUCK

    // scratch inside d_out (dead until agg_gemm writes out):
    unsigned* pairs    = (unsigned*)d_out;                   // E uint32 (6.4 MB)
    int*     blockhist = (int*)d_out + 2097152;              // at +8 MB: C_BLOCKS*NBUCK ints

    hipMemsetAsync(bhist, 0, NBUCK * sizeof(int), stream);
    bucket_hist_kernel<<<C_BLOCKS, 256, 0, stream>>>(dst, bhist, blockhist);
    bucket_scan_kernel<<<1, 512, 0, stream>>>(bhist, bucket_offs, bucket_cur, offs);
    binscatter_kernel<<<C_BLOCKS, 256, 0, stream>>>(src, dst, blockhist, bucket_cur, pairs);
    bucket_build_kernel<<<NBUCK, 256, 0, stream>>>(pairs, bucket_offs, offs, eidx);

    gemm1_kernel<<<N_NODES / 32, 256, 0, stream>>>(x, W, hb);
    agg_gemm_kernel<<<N_NODES / 16, 256, 0, stream>>>(hb, norm, V, offs, eidx, out);
}